// Round 10
// baseline (428.927 us; speedup 1.0000x reference)
//
#include <hip/hip_runtime.h>

// Persistent-RNN v7: K-SPLIT wave pairs. 256 blocks (1/CU) x 512 threads.
// Waves (p,q): p in 0..3 owns 5 N-tiles (p=3: 4), q in {0,1} owns half the
// K-chunks. Per-wave weights: 35 half8 = 140 regs -> fits the 256-reg/wave
// budget that 8-wave blocks get on gfx950 (512-reg SIMD file / 2 waves),
// measured R2/R4/R9: launch_bounds cannot raise it; footprint must shrink.
// Per step: MFMA partials (both q) -> q0 writes f32 partials to LDS (b128,
// conflict-free) + stages xe(t+1) -> barrier -> q1 combines+bias+tanh,
// writes h(t+1) -> barrier. A-panel reads per wave halve (7 b128 vs 14).
// MFMA 16x16x32_f16: A/B: k = 8*(lane>>4)+j contiguous; D: col=lane&15,
// row=4*(lane>>4)+j (verified R1-R9, absmax 9.8e-4).

#define SEQ    200
#define BATCHN 4096
#define EMBD   100
#define HIDN   300

#define KCHF  10     // full hidden K-chunks of 32 (320, for fc1)
#define KCHH  5      // hidden K-chunks per half
#define KCEH  2      // emb K-chunks per half
#define XE0   320    // xe column offset within a buffer (f16 elems)
#define BSPAN 448    // one buffer span (320 h + 128 xe)
#define SROW  904    // 2*BSPAN + 8 pad (f16 elems; 1808 B/row)
#define ROWS  16
#define NT    5      // max N-tiles per p-group

typedef _Float16 half8 __attribute__((ext_vector_type(8)));
typedef float    f32x4 __attribute__((ext_vector_type(4)));

static __device__ __forceinline__ f32x4 f4z() { f32x4 z = {0.f, 0.f, 0.f, 0.f}; return z; }

static __device__ __forceinline__ half8 h8cvt(f32x4 a, f32x4 b) {
  half8 h;
  h[0]=(_Float16)a[0]; h[1]=(_Float16)a[1]; h[2]=(_Float16)a[2]; h[3]=(_Float16)a[3];
  h[4]=(_Float16)b[0]; h[5]=(_Float16)b[1]; h[6]=(_Float16)b[2]; h[7]=(_Float16)b[3];
  return h;
}

// Load 8 f16 of row[k0..k0+7], zero-padded past kmax (kmax % 4 == 0 for all uses).
static __device__ __forceinline__ half8 loadw(const float* row, int k0, int kmax, bool nv) {
  f32x4 a = (nv && (k0 + 3 < kmax)) ? *(const f32x4*)(row + k0)     : f4z();
  f32x4 b = (nv && (k0 + 7 < kmax)) ? *(const f32x4*)(row + k0 + 4) : f4z();
  return h8cvt(a, b);
}

static __device__ __forceinline__ float tanh_fast(float x) {
  float e = __builtin_amdgcn_exp2f(x * 2.8853900817779268f);  // exp(2x)
  float r = __builtin_amdgcn_rcpf(e + 1.0f);
  return __builtin_fmaf(-2.0f, r, 1.0f);
}

#define MFMA32(A,B,C) __builtin_amdgcn_mfma_f32_16x16x32_f16((A),(B),(C),0,0,0)

#define STEP_BODY(NT_) do {                                                   \
    _Pragma("unroll")                                                         \
    for (int c = 0; c < KCHH; c++) {                                          \
      const half8 a = *(const half8*)(ab + (kh0 + c) * 32);                   \
      acc[0] = MFMA32(a, whh[c][0], acc[0]);                                  \
      acc[1] = MFMA32(a, whh[c][1], acc[1]);                                  \
      acc[2] = MFMA32(a, whh[c][2], acc[2]);                                  \
      acc[3] = MFMA32(a, whh[c][3], acc[3]);                                  \
      if (NT_ == 5) acc[4] = MFMA32(a, whh[c][4], acc[4]);                    \
    }                                                                         \
    _Pragma("unroll")                                                         \
    for (int c = 0; c < KCEH; c++) {                                          \
      const half8 a = *(const half8*)(ab + XE0 + (ke0 + c) * 32);             \
      acc[0] = MFMA32(a, wih[c][0], acc[0]);                                  \
      acc[1] = MFMA32(a, wih[c][1], acc[1]);                                  \
      acc[2] = MFMA32(a, wih[c][2], acc[2]);                                  \
      acc[3] = MFMA32(a, wih[c][3], acc[3]);                                  \
      if (NT_ == 5) acc[4] = MFMA32(a, wih[c][4], acc[4]);                    \
    }                                                                         \
  } while (0)

__global__ __launch_bounds__(512, 1)
void rnn_fused(const int* __restrict__ x, const float* __restrict__ emb,
               const float* __restrict__ w_ih, const float* __restrict__ w_hh,
               const float* __restrict__ b_ih, const float* __restrict__ b_hh,
               const float* __restrict__ fc1w, const float* __restrict__ fc1b,
               const float* __restrict__ fc2w, const float* __restrict__ fc2b,
               float* __restrict__ out)
{
  __shared__ __align__(16) _Float16 s_lds[ROWS][SROW]; // 2 x (h 320 | xe 128)
  __shared__ __align__(16) float    pbuf[19][16][16];  // K-half partial sums
  __shared__ __align__(16) float    h1f[ROWS][257];    // fc1 output
  __shared__ int x_lds[SEQ][16];

  const int tid  = (int)threadIdx.x;
  const int lane = tid & 63;
  const int wv   = tid >> 6;
  const int r    = lane & 15;   // A-row / B-col / D-col lane index
  const int g    = lane >> 4;   // k-group 0..3 (k = 8g + j)
  const int base = (int)blockIdx.x * ROWS;

  const int p = wv & 3;         // N-group
  const int q = wv >> 2;        // K-half
  const int t0    = p * NT;
  const int ntile = (p < 3) ? NT : 4;     // 19 tiles total
  const int kh0   = q * KCHH;   // hidden chunk base for this half
  const int ke0   = q * KCEH;   // emb chunk base for this half

  // ---- stage x indices for this block's 16 rows (all 200 steps)
  for (int i = tid; i < SEQ * 16; i += 512)
    x_lds[i >> 4][i & 15] = x[(i >> 4) * BATCHN + base + (i & 15)];
  // ---- zero both h/xe buffers (padding cols must stay zero)
  for (int i = tid; i < ROWS * SROW; i += 512)
    (&s_lds[0][0])[i] = (_Float16)0.f;

  // ---- resident weight fragments (f16) + bias: 35 half8 = 140 regs/wave
  half8 whh[KCHH][NT];
  half8 wih[KCEH][NT];
  float bias[NT];
  #pragma unroll
  for (int tt = 0; tt < NT; tt++) {
    const int n = (t0 + tt) * 16 + r;
    const bool nv = (tt < ntile) && (n < HIDN);
    bias[tt] = nv ? (b_ih[n] + b_hh[n]) : 0.f;
    #pragma unroll
    for (int c = 0; c < KCHH; c++)
      whh[c][tt] = loadw(w_hh + (long)n * HIDN, (kh0 + c) * 32 + 8 * g, HIDN, nv);
    #pragma unroll
    for (int c = 0; c < KCEH; c++)
      wih[c][tt] = loadw(w_ih + (long)n * EMBD, (ke0 + c) * 32 + 8 * g, EMBD, nv);
  }

  // xe gather (q==0 waves): lane -> (row rr, half8 slot sl), 4x64 lanes = 256 slots
  const int rr = lane & 15;
  const int sl = p * 4 + (lane >> 4);    // 0..15, k0 = 8*sl
  const int k0 = 8 * sl;

  __syncthreads();

  // ---- pre-stage xe(t=0) into buffer 0
  if (q == 0) {
    const int idx = x_lds[0][rr];
    const float* erow = emb + (long)idx * EMBD;
    f32x4 a = (k0 + 3 < EMBD) ? *(const f32x4*)(erow + k0)     : f4z();
    f32x4 b = (k0 + 7 < EMBD) ? *(const f32x4*)(erow + k0 + 4) : f4z();
    *(half8*)&s_lds[rr][XE0 + k0] = h8cvt(a, b);
  }
  __syncthreads();

  const _Float16* a_base = &s_lds[r][8 * g];

  // =========================== main scan ===========================
  #pragma unroll 2
  for (int t = 0; t < SEQ; t++) {
    const _Float16* ab = a_base + (t & 1) * BSPAN;    // read buffer
    const int nbuf = ((t + 1) & 1) * BSPAN;           // write buffer (col offset)

    // issue next-step emb gathers early (latency hides under MFMAs)
    f32x4 xga, xgb;
    if (q == 0) {
      const int tn = (t + 1 < SEQ) ? t + 1 : t;
      const int idx = x_lds[tn][rr];
      const float* erow = emb + (long)idx * EMBD;
      xga = (k0 + 3 < EMBD) ? *(const f32x4*)(erow + k0)     : f4z();
      xgb = (k0 + 7 < EMBD) ? *(const f32x4*)(erow + k0 + 4) : f4z();
    }

    f32x4 acc[NT];
    #pragma unroll
    for (int tt = 0; tt < NT; tt++) {
      const float bb = q ? bias[tt] : 0.f;     // bias counted once (q=1 side)
      f32x4 v = {bb, bb, bb, bb};
      acc[tt] = v;
    }

    if (ntile == 5) { STEP_BODY(5); } else { STEP_BODY(4); }

    if (q == 0) {
      // write K-half partials: b128, lanes cover 1KB contiguous -> conflict-free
      #pragma unroll
      for (int tt = 0; tt < NT; tt++)
        if (tt < ntile)
          *(f32x4*)&pbuf[t0 + tt][r][4 * g] = acc[tt];
      // stage xe(t+1) into the other buffer
      *(half8*)&s_lds[rr][nbuf + XE0 + k0] = h8cvt(xga, xgb);
    }
    __syncthreads();   // partials + xe visible

    if (q == 1) {
      // combine halves + tanh; D: row m = 4g+j, col n = (t0+tt)*16 + r
      #pragma unroll
      for (int tt = 0; tt < NT; tt++) {
        if (tt < ntile) {
          const int n = (t0 + tt) * 16 + r;
          if (n < HIDN) {
            const f32x4 part = *(const f32x4*)&pbuf[t0 + tt][r][4 * g];
            #pragma unroll
            for (int j = 0; j < 4; j++)
              s_lds[4 * g + j][nbuf + n] = (_Float16)tanh_fast(acc[tt][j] + part[j]);
          }
        }
      }
    }
    __syncthreads();   // h(t+1) visible before step t+1 reads
  }

  // =========================== fc1 (relu) ===========================
  {
    const _Float16* abf = a_base + (SEQ & 1) * BSPAN;  // h(SEQ) buffer (SEQ even -> buf 0)
    f32x4 acc1[2];
    const int f0 = wv * 2;   // 16 n-tiles over 8 waves
    #pragma unroll
    for (int ft = 0; ft < 2; ft++) {
      const float bb = fc1b[(f0 + ft) * 16 + r];
      f32x4 v = {bb, bb, bb, bb};
      acc1[ft] = v;
    }
    #pragma unroll
    for (int c = 0; c < KCHF; c++) {
      const half8 a = *(const half8*)(abf + c * 32);
      #pragma unroll
      for (int ft = 0; ft < 2; ft++) {
        const int n = (f0 + ft) * 16 + r;
        const half8 b = loadw(fc1w + (long)n * HIDN, c * 32 + 8 * g, HIDN, true);
        acc1[ft] = MFMA32(a, b, acc1[ft]);
      }
    }
    #pragma unroll
    for (int ft = 0; ft < 2; ft++) {
      const int n = (f0 + ft) * 16 + r;
      #pragma unroll
      for (int j = 0; j < 4; j++) {
        const float v = acc1[ft][j];
        h1f[4 * g + j][n] = v > 0.f ? v : 0.f;
      }
    }
  }
  __syncthreads();

  // =========================== fc2 (fp32 scalar) ===========================
  if (wv == 0 && lane < 48) {
    const int m = lane / 3;
    const int n = lane - 3 * m;
    float s = fc2b[n];
    for (int k = 0; k < 256; k++)
      s = __builtin_fmaf(h1f[m][k], fc2w[n * 256 + k], s);
    out[(base + m) * 3 + n] = s;
  }
}

extern "C" void kernel_launch(void* const* d_in, const int* in_sizes, int n_in,
                              void* d_out, int out_size, void* d_ws, size_t ws_size,
                              hipStream_t stream) {
  (void)in_sizes; (void)n_in; (void)d_ws; (void)ws_size; (void)out_size;
  const int*   x   = (const int*)d_in[0];
  const float* emb = (const float*)d_in[1];
  const float* wih = (const float*)d_in[2];
  const float* whh = (const float*)d_in[3];
  const float* bih = (const float*)d_in[4];
  const float* bhh = (const float*)d_in[5];
  const float* f1w = (const float*)d_in[6];
  const float* f1b = (const float*)d_in[7];
  const float* f2w = (const float*)d_in[8];
  const float* f2b = (const float*)d_in[9];
  rnn_fused<<<BATCHN / ROWS, 512, 0, stream>>>(
      x, emb, wih, whh, bih, bhh, f1w, f1b, f2w, f2b, (float*)d_out);
}